// Round 1
// baseline (1168.147 us; speedup 1.0000x reference)
//
#include <hip/hip_runtime.h>
#include <stdint.h>

#define Bb 8
#define Tt 32
#define Ee 4096
#define NQ 32
#define NKV 8
#define HD 128
#define CACHE_S 8192
#define SSPLIT 4
#define SCALE_F 0.08838834764831845f  // 1/sqrt(128)

typedef _Float16 half8 __attribute__((ext_vector_type(8)));
typedef _Float16 half4 __attribute__((ext_vector_type(4)));
typedef float f32x4 __attribute__((ext_vector_type(4)));

static __device__ __forceinline__ _Float16 f2h(float f) { return (_Float16)f; }

// ---------------------------------------------------------------------------
// GEMM: C[M x N] (leading dim ldc) = A[M x K] * W[N x K]^T ; fp32 in/out,
// f16 MFMA inside. M,N multiples of 128; K multiple of 64.
// ---------------------------------------------------------------------------
__global__ __launch_bounds__(256) void gemm_nt(
    const float* __restrict__ A, const float* __restrict__ W,
    float* __restrict__ C, int M, int N, int K, int ldc) {
  __shared__ _Float16 As[128][72];  // +8 pad: 2-way max bank aliasing on b128
  __shared__ _Float16 Ws[128][72];
  const int n0 = blockIdx.x * 128;
  const int m0 = blockIdx.y * 128;
  const int tid = threadIdx.x;
  const int lane = tid & 63;
  const int wave = tid >> 6;
  const int wm = (wave >> 1) * 64;
  const int wn = (wave & 1) * 64;
  const int l15 = lane & 15;
  const int quad = lane >> 4;
  const int sr = tid >> 4;         // staging row 0..15 (+p*16)
  const int sc = (tid & 15) * 4;   // staging col (floats)

  f32x4 acc[4][4];
#pragma unroll
  for (int i = 0; i < 4; i++)
#pragma unroll
    for (int j = 0; j < 4; j++) acc[i][j] = f32x4{0.f, 0.f, 0.f, 0.f};

  for (int k0 = 0; k0 < K; k0 += 64) {
    __syncthreads();
#pragma unroll
    for (int p = 0; p < 8; p++) {
      const int r = sr + p * 16;
      float4 va = *(const float4*)&A[(size_t)(m0 + r) * K + (k0 + sc)];
      half4 ha = {f2h(va.x), f2h(va.y), f2h(va.z), f2h(va.w)};
      *(half4*)&As[r][sc] = ha;
      float4 vb = *(const float4*)&W[(size_t)(n0 + r) * K + (k0 + sc)];
      half4 hb = {f2h(vb.x), f2h(vb.y), f2h(vb.z), f2h(vb.w)};
      *(half4*)&Ws[r][sc] = hb;
    }
    __syncthreads();
#pragma unroll
    for (int ks = 0; ks < 2; ks++) {
      const int kc = ks * 32 + quad * 8;
      half8 af[4], wf[4];
#pragma unroll
      for (int i = 0; i < 4; i++) {
        af[i] = *(const half8*)&As[wm + i * 16 + l15][kc];
        wf[i] = *(const half8*)&Ws[wn + i * 16 + l15][kc];
      }
#pragma unroll
      for (int i = 0; i < 4; i++)
#pragma unroll
        for (int j = 0; j < 4; j++)
          acc[i][j] = __builtin_amdgcn_mfma_f32_16x16x32_f16(af[i], wf[j],
                                                             acc[i][j], 0, 0, 0);
    }
  }
#pragma unroll
  for (int i = 0; i < 4; i++) {
    const int mr = m0 + wm + i * 16 + quad * 4;
#pragma unroll
    for (int j = 0; j < 4; j++) {
      const int nc = n0 + wn + j * 16 + l15;
#pragma unroll
      for (int r = 0; r < 4; r++)
        C[(size_t)(mr + r) * ldc + nc] = acc[i][j][r];
    }
  }
}

// ---------------------------------------------------------------------------
// RoPE (bugged variant: angle depends on HEAD index, not position) + scatter
// qkv (256 x 6144) -> qw (B,NQ,T,HD), kw (B,NKV,T,HD), vw (B,NKV,T,HD)
// One thread per (row, even/odd pair).
// ---------------------------------------------------------------------------
__global__ __launch_bounds__(256) void rope_scatter(
    const float* __restrict__ qkv, float* __restrict__ qw,
    float* __restrict__ kw, float* __restrict__ vw) {
  const int pid = blockIdx.x * 256 + threadIdx.x;  // 0 .. 256*3072
  const int m = pid / 3072;
  const int c = pid - m * 3072;
  const int n = c * 2;
  const int b = m >> 5;
  const int t = m & 31;
  const float a0 = qkv[(size_t)m * 6144 + n];
  const float a1 = qkv[(size_t)m * 6144 + n + 1];
  if (n < 4096) {  // q
    const int h = n >> 7;
    const int j = (n & 127) >> 1;
    const float invf = powf(10000.0f, -(float)j * (1.0f / 64.0f));
    float sn, cs;
    sincosf((float)h * invf, &sn, &cs);
    float* dst = qw + ((size_t)(b * NQ + h) * Tt + t) * HD + (j << 1);
    dst[0] = a0 * cs - a1 * sn;
    dst[1] = a0 * sn + a1 * cs;
  } else if (n < 5120) {  // k (rope'd)
    const int nn = n - 4096;
    const int h = nn >> 7;
    const int j = (nn & 127) >> 1;
    const float invf = powf(10000.0f, -(float)j * (1.0f / 64.0f));
    float sn, cs;
    sincosf((float)h * invf, &sn, &cs);
    float* dst = kw + ((size_t)(b * NKV + h) * Tt + t) * HD + (j << 1);
    dst[0] = a0 * cs - a1 * sn;
    dst[1] = a0 * sn + a1 * cs;
  } else {  // v passthrough
    const int nn = n - 5120;
    const int h = nn >> 7;
    const int d = nn & 127;
    float* dst = vw + ((size_t)(b * NKV + h) * Tt + t) * HD + d;
    dst[0] = a0;
    dst[1] = a1;
  }
}

// ---------------------------------------------------------------------------
// Flash-decode attention partials. Block = (b, kv-head g, split). 4 waves,
// wave w handles q-head h = g*4+w (GQA). K/V chunk (32 keys) staged in LDS
// (V transposed). Online softmax, unnormalized O + (m,l) per split.
// ---------------------------------------------------------------------------
__global__ __launch_bounds__(256) void attn_partial(
    const float* __restrict__ qw, const float* __restrict__ kw,
    const float* __restrict__ vw, const float* __restrict__ cacheK,
    const float* __restrict__ cacheV, const int* __restrict__ startp,
    float* __restrict__ pO, float* __restrict__ pM, float* __restrict__ pL) {
  const int blk = blockIdx.x;
  const int split = blk & (SSPLIT - 1);
  const int g = (blk >> 2) & (NKV - 1);
  const int b = blk >> 5;
  const int start = *startp;
  const int end = start + Tt;
  int cl = ((end + SSPLIT * 32 - 1) / (SSPLIT * 32)) * 32;
  const int s_begin = split * cl;
  int s_end = s_begin + cl;
  if (s_end > end) s_end = end;

  const int tid = threadIdx.x;
  const int lane = tid & 63;
  const int wave = tid >> 6;
  const int l15 = lane & 15;
  const int quad = lane >> 4;
  const int h = g * 4 + wave;

  __shared__ _Float16 Ks[32][136];     // 32 keys x 128 d (+8 pad)
  __shared__ _Float16 Vt[128][40];     // transposed: d x 32 keys (+8 pad)
  __shared__ _Float16 Ps[4][32][40];   // per-wave P: t x 32 keys (+8 pad)

  // Q fragments (A-operand): qf[mt][ks], t = mt*16+l15, d = ks*32+quad*8+j
  half8 qf[2][4];
#pragma unroll
  for (int mt = 0; mt < 2; mt++) {
    const int t = mt * 16 + l15;
    const float* qrow = qw + ((size_t)(b * NQ + h) * Tt + t) * HD;
#pragma unroll
    for (int ks = 0; ks < 4; ks++) {
      const int d0 = ks * 32 + quad * 8;
      float4 v0 = *(const float4*)&qrow[d0];
      float4 v1 = *(const float4*)&qrow[d0 + 4];
      half8 hq = {f2h(v0.x), f2h(v0.y), f2h(v0.z), f2h(v0.w),
                  f2h(v1.x), f2h(v1.y), f2h(v1.z), f2h(v1.w)};
      qf[mt][ks] = hq;
    }
  }

  f32x4 Oacc[2][8];
#pragma unroll
  for (int mt = 0; mt < 2; mt++)
#pragma unroll
    for (int dt = 0; dt < 8; dt++) Oacc[mt][dt] = f32x4{0.f, 0.f, 0.f, 0.f};
  float mrow[2][4], lrow[2][4];
#pragma unroll
  for (int mt = 0; mt < 2; mt++)
#pragma unroll
    for (int rr = 0; rr < 4; rr++) { mrow[mt][rr] = -1e30f; lrow[mt][rr] = 0.f; }

  for (int s0 = s_begin; s0 < s_end; s0 += 32) {
    __syncthreads();
    // ---- stage K (f16) and V^T (f16) for keys s0..s0+31 ----
    {
      const int r = tid >> 3;        // key row 0..31
      const int sg = s0 + r;
      const bool valid = sg < end;
      const float* krow;
      const float* vrow;
      if (sg < start) {
        const size_t off = (((size_t)b * CACHE_S + sg) * NKV + g) * HD;
        krow = cacheK + off;
        vrow = cacheV + off;
      } else {
        int loc = sg - start;
        if (loc > Tt - 1) loc = Tt - 1;  // clamp (guarded by `valid`)
        const size_t off = ((size_t)(b * NKV + g) * Tt + loc) * HD;
        krow = kw + off;
        vrow = vw + off;
      }
#pragma unroll
      for (int u = 0; u < 4; u++) {
        const int cc = (tid & 7) * 4 + u * 32;
        float4 kv = valid ? *(const float4*)&krow[cc] : make_float4(0.f, 0.f, 0.f, 0.f);
        half4 hk = {f2h(kv.x), f2h(kv.y), f2h(kv.z), f2h(kv.w)};
        *(half4*)&Ks[r][cc] = hk;
        float4 vv = valid ? *(const float4*)&vrow[cc] : make_float4(0.f, 0.f, 0.f, 0.f);
        Vt[cc + 0][r] = f2h(vv.x);
        Vt[cc + 1][r] = f2h(vv.y);
        Vt[cc + 2][r] = f2h(vv.z);
        Vt[cc + 3][r] = f2h(vv.w);
      }
    }
    __syncthreads();

    // ---- scores S[t][s] = sum_d Q K ----
    f32x4 st[2][2];
#pragma unroll
    for (int mt = 0; mt < 2; mt++)
#pragma unroll
      for (int nt = 0; nt < 2; nt++) st[mt][nt] = f32x4{0.f, 0.f, 0.f, 0.f};
#pragma unroll
    for (int nt = 0; nt < 2; nt++) {
#pragma unroll
      for (int ks = 0; ks < 4; ks++) {
        half8 kf = *(const half8*)&Ks[nt * 16 + l15][ks * 32 + quad * 8];
        st[0][nt] = __builtin_amdgcn_mfma_f32_16x16x32_f16(qf[0][ks], kf, st[0][nt], 0, 0, 0);
        st[1][nt] = __builtin_amdgcn_mfma_f32_16x16x32_f16(qf[1][ks], kf, st[1][nt], 0, 0, 0);
      }
    }
    // scale + causal/end mask. element: t = mt*16+quad*4+rr, s = s0+nt*16+l15
#pragma unroll
    for (int mt = 0; mt < 2; mt++)
#pragma unroll
      for (int nt = 0; nt < 2; nt++)
#pragma unroll
        for (int rr = 0; rr < 4; rr++) {
          const int t = mt * 16 + quad * 4 + rr;
          const int sg = s0 + nt * 16 + l15;
          const float sv = st[mt][nt][rr] * SCALE_F;
          const bool masked = (sg > start + t) || (sg >= end);
          st[mt][nt][rr] = masked ? -1e30f : sv;
        }
    // ---- online softmax ----
#pragma unroll
    for (int mt = 0; mt < 2; mt++) {
      float rmax[4], rsum[4], al[4];
#pragma unroll
      for (int rr = 0; rr < 4; rr++)
        rmax[rr] = fmaxf(st[mt][0][rr], st[mt][1][rr]);
      for (int mm = 1; mm < 16; mm <<= 1)
#pragma unroll
        for (int rr = 0; rr < 4; rr++)
          rmax[rr] = fmaxf(rmax[rr], __shfl_xor(rmax[rr], mm));
#pragma unroll
      for (int rr = 0; rr < 4; rr++) {
        const float mn = fmaxf(mrow[mt][rr], rmax[rr]);
        al[rr] = __expf(mrow[mt][rr] - mn);
        mrow[mt][rr] = mn;
      }
#pragma unroll
      for (int nt = 0; nt < 2; nt++)
#pragma unroll
        for (int rr = 0; rr < 4; rr++)
          st[mt][nt][rr] = __expf(st[mt][nt][rr] - mrow[mt][rr]);
#pragma unroll
      for (int rr = 0; rr < 4; rr++) rsum[rr] = st[mt][0][rr] + st[mt][1][rr];
      for (int mm = 1; mm < 16; mm <<= 1)
#pragma unroll
        for (int rr = 0; rr < 4; rr++) rsum[rr] += __shfl_xor(rsum[rr], mm);
#pragma unroll
      for (int rr = 0; rr < 4; rr++)
        lrow[mt][rr] = lrow[mt][rr] * al[rr] + rsum[rr];
      // write P (C-layout -> LDS), rescale O
#pragma unroll
      for (int nt = 0; nt < 2; nt++)
#pragma unroll
        for (int rr = 0; rr < 4; rr++)
          Ps[wave][mt * 16 + quad * 4 + rr][nt * 16 + l15] = f2h(st[mt][nt][rr]);
#pragma unroll
      for (int dt = 0; dt < 8; dt++)
#pragma unroll
        for (int rr = 0; rr < 4; rr++) Oacc[mt][dt][rr] *= al[rr];
    }
    // ---- PV: O[t][d] += P[t][s] V[s][d] (s-chunk = 32 = one MFMA k-step) ----
    half8 pf0 = *(const half8*)&Ps[wave][l15][quad * 8];
    half8 pf1 = *(const half8*)&Ps[wave][16 + l15][quad * 8];
#pragma unroll
    for (int dt = 0; dt < 8; dt++) {
      half8 vf = *(const half8*)&Vt[dt * 16 + l15][quad * 8];
      Oacc[0][dt] = __builtin_amdgcn_mfma_f32_16x16x32_f16(pf0, vf, Oacc[0][dt], 0, 0, 0);
      Oacc[1][dt] = __builtin_amdgcn_mfma_f32_16x16x32_f16(pf1, vf, Oacc[1][dt], 0, 0, 0);
    }
  }

  // ---- write partials ----
  const size_t rowbase = (size_t)(b * NQ + h) * Tt;
#pragma unroll
  for (int mt = 0; mt < 2; mt++)
#pragma unroll
    for (int rr = 0; rr < 4; rr++) {
      const int t = mt * 16 + quad * 4 + rr;
      const size_t pbase = ((rowbase + t) * SSPLIT + split) * (size_t)HD;
#pragma unroll
      for (int dt = 0; dt < 8; dt++)
        pO[pbase + dt * 16 + l15] = Oacc[mt][dt][rr];
      if (l15 == 0) {
        pM[(rowbase + t) * SSPLIT + split] = mrow[mt][rr];
        pL[(rowbase + t) * SSPLIT + split] = lrow[mt][rr];
      }
    }
}

// ---------------------------------------------------------------------------
// Combine split partials -> att (B,T, NQ*HD) laid out for the Wo GEMM.
// ---------------------------------------------------------------------------
__global__ __launch_bounds__(128) void attn_combine(
    const float* __restrict__ pO, const float* __restrict__ pM,
    const float* __restrict__ pL, float* __restrict__ att) {
  const int row = blockIdx.x;  // (b*NQ + h)*T + t
  const int d = threadIdx.x;
  float m[SSPLIT], l[SSPLIT];
  float ms = -3.0e30f;
#pragma unroll
  for (int i = 0; i < SSPLIT; i++) {
    m[i] = pM[row * SSPLIT + i];
    l[i] = pL[row * SSPLIT + i];
    ms = fmaxf(ms, m[i]);
  }
  float ls = 0.f, o = 0.f;
#pragma unroll
  for (int i = 0; i < SSPLIT; i++) {
    const float w = __expf(m[i] - ms);
    ls += l[i] * w;
    o += pO[((size_t)row * SSPLIT + i) * HD + d] * w;
  }
  o /= fmaxf(ls, 1e-30f);
  const int b = row / (NQ * Tt);
  const int hh = (row / Tt) % NQ;
  const int t = row % Tt;
  att[((size_t)(b * Tt + t)) * Ee + hh * HD + d] = o;
}

// ---------------------------------------------------------------------------
extern "C" void kernel_launch(void* const* d_in, const int* in_sizes, int n_in,
                              void* d_out, int out_size, void* d_ws,
                              size_t ws_size, hipStream_t stream) {
  const float* x = (const float*)d_in[0];
  const int* startp = (const int*)d_in[1];
  const float* cacheK = (const float*)d_in[2];
  const float* cacheV = (const float*)d_in[3];
  const float* Wq = (const float*)d_in[4];
  const float* Wk = (const float*)d_in[5];
  const float* Wv = (const float*)d_in[6];
  const float* Wo = (const float*)d_in[7];
  float* out = (float*)d_out;
  float* ws = (float*)d_ws;

  // workspace layout (floats). qkv region reused for pO after rope consumes it.
  float* qkv = ws;                    // 256*6144 = 1,572,864 (dead after rope)
  float* pO = ws;                     // 8192*4*128 = 4,194,304
  float* qw = ws + 4194304;           // 1,048,576
  float* kw = qw + 1048576;           // 262,144
  float* vw = kw + 262144;            // 262,144
  float* pM = vw + 262144;            // 32,768
  float* pL = pM + 32768;             // 32,768
  float* att = pL + 32768;            // 1,048,576

  const dim3 blk(256);
  // QKV projections (N-regions share qkv with ldc = 6144)
  gemm_nt<<<dim3(32, 2), blk, 0, stream>>>(x, Wq, qkv, 256, 4096, 4096, 6144);
  gemm_nt<<<dim3(8, 2), blk, 0, stream>>>(x, Wk, qkv + 4096, 256, 1024, 4096, 6144);
  gemm_nt<<<dim3(8, 2), blk, 0, stream>>>(x, Wv, qkv + 5120, 256, 1024, 4096, 6144);
  // RoPE (head-index bug replicated) + scatter to attention layouts
  rope_scatter<<<dim3(3072), blk, 0, stream>>>(qkv, qw, kw, vw);
  // Flash-decode attention partials over 4 S-splits
  attn_partial<<<dim3(Bb * NKV * SSPLIT), blk, 0, stream>>>(
      qw, kw, vw, cacheK, cacheV, startp, pO, pM, pL);
  // Combine splits
  attn_combine<<<dim3(Bb * NQ * Tt), dim3(128), 0, stream>>>(pO, pM, pL, att);
  // Output projection
  gemm_nt<<<dim3(32, 2), blk, 0, stream>>>(att, Wo, out, 256, 4096, 4096, 4096);
}

// Round 2
// 754.552 us; speedup vs baseline: 1.5481x; 1.5481x over previous
//
#include <hip/hip_runtime.h>
#include <stdint.h>

#define Bb 8
#define Tt 32
#define Ee 4096
#define NQ 32
#define NKV 8
#define HD 128
#define CACHE_S 8192
#define SSPLIT 8
#define SCALE_F 0.08838834764831845f  // 1/sqrt(128)

typedef _Float16 half8 __attribute__((ext_vector_type(8)));
typedef _Float16 half4 __attribute__((ext_vector_type(4)));
typedef float f32x4 __attribute__((ext_vector_type(4)));

static __device__ __forceinline__ _Float16 f2h(float f) { return (_Float16)f; }

// ---------------------------------------------------------------------------
// GEMM: C[M x N] (ld ldc) = A[M x K] * W[N x K]^T, fp32 in/out, f16 MFMA.
// 64x64 tiles, register double-buffered staging. Second weight matrix W2
// used for n >= n_split (fused Wk|Wv launch); pass W2=W, n_split=N otherwise.
// ---------------------------------------------------------------------------
__global__ __launch_bounds__(256) void gemm_nt(
    const float* __restrict__ A, const float* __restrict__ W,
    const float* __restrict__ W2, int n_split,
    float* __restrict__ C, int K, int ldc) {
  __shared__ _Float16 As[64][72];
  __shared__ _Float16 Ws[64][72];
  const int n0 = blockIdx.x * 64;
  const int m0 = blockIdx.y * 64;
  const float* Wp = (n0 < n_split) ? W : W2;
  const int nr0 = (n0 < n_split) ? n0 : (n0 - n_split);
  const int tid = threadIdx.x;
  const int lane = tid & 63;
  const int wave = tid >> 6;
  const int wm = (wave >> 1) * 32;
  const int wn = (wave & 1) * 32;
  const int l15 = lane & 15;
  const int quad = lane >> 4;
  const int sr = tid >> 4;        // staging row 0..15 (+p*16)
  const int sc = (tid & 15) * 4;  // staging col (floats)

  f32x4 acc[2][2];
#pragma unroll
  for (int i = 0; i < 2; i++)
#pragma unroll
    for (int j = 0; j < 2; j++) acc[i][j] = f32x4{0.f, 0.f, 0.f, 0.f};

  float4 pa[4], pw[4];
  // preload k0 = 0
#pragma unroll
  for (int p = 0; p < 4; p++) {
    const int r = sr + p * 16;
    pa[p] = *(const float4*)&A[(size_t)(m0 + r) * K + sc];
    pw[p] = *(const float4*)&Wp[(size_t)(nr0 + r) * K + sc];
  }

  for (int k0 = 0; k0 < K; k0 += 64) {
    __syncthreads();
#pragma unroll
    for (int p = 0; p < 4; p++) {
      const int r = sr + p * 16;
      half4 ha = {f2h(pa[p].x), f2h(pa[p].y), f2h(pa[p].z), f2h(pa[p].w)};
      *(half4*)&As[r][sc] = ha;
      half4 hw = {f2h(pw[p].x), f2h(pw[p].y), f2h(pw[p].z), f2h(pw[p].w)};
      *(half4*)&Ws[r][sc] = hw;
    }
    __syncthreads();
    // prefetch next K-tile (overlaps with MFMA below)
    if (k0 + 64 < K) {
#pragma unroll
      for (int p = 0; p < 4; p++) {
        const int r = sr + p * 16;
        pa[p] = *(const float4*)&A[(size_t)(m0 + r) * K + (k0 + 64 + sc)];
        pw[p] = *(const float4*)&Wp[(size_t)(nr0 + r) * K + (k0 + 64 + sc)];
      }
    }
#pragma unroll
    for (int ks = 0; ks < 2; ks++) {
      const int kc = ks * 32 + quad * 8;
      half8 af[2], wf[2];
#pragma unroll
      for (int i = 0; i < 2; i++) {
        af[i] = *(const half8*)&As[wm + i * 16 + l15][kc];
        wf[i] = *(const half8*)&Ws[wn + i * 16 + l15][kc];
      }
#pragma unroll
      for (int i = 0; i < 2; i++)
#pragma unroll
        for (int j = 0; j < 2; j++)
          acc[i][j] = __builtin_amdgcn_mfma_f32_16x16x32_f16(af[i], wf[j],
                                                             acc[i][j], 0, 0, 0);
    }
  }
#pragma unroll
  for (int i = 0; i < 2; i++) {
    const int mr = m0 + wm + i * 16 + quad * 4;
#pragma unroll
    for (int j = 0; j < 2; j++) {
      const int nc = n0 + wn + j * 16 + l15;
#pragma unroll
      for (int r = 0; r < 4; r++)
        C[(size_t)(mr + r) * ldc + nc] = acc[i][j][r];
    }
  }
}

// ---------------------------------------------------------------------------
// RoPE (bugged variant: angle depends on HEAD index, not position) + scatter
// qkv (256 x 6144) -> qw (B,NQ,T,HD), kw (B,NKV,T,HD), vw (B,NKV,T,HD)
// ---------------------------------------------------------------------------
__global__ __launch_bounds__(256) void rope_scatter(
    const float* __restrict__ qkv, float* __restrict__ qw,
    float* __restrict__ kw, float* __restrict__ vw) {
  const int pid = blockIdx.x * 256 + threadIdx.x;
  const int m = pid / 3072;
  const int c = pid - m * 3072;
  const int n = c * 2;
  const int b = m >> 5;
  const int t = m & 31;
  const float a0 = qkv[(size_t)m * 6144 + n];
  const float a1 = qkv[(size_t)m * 6144 + n + 1];
  if (n < 4096) {  // q
    const int h = n >> 7;
    const int j = (n & 127) >> 1;
    const float invf = powf(10000.0f, -(float)j * (1.0f / 64.0f));
    float sn, cs;
    sincosf((float)h * invf, &sn, &cs);
    float* dst = qw + ((size_t)(b * NQ + h) * Tt + t) * HD + (j << 1);
    dst[0] = a0 * cs - a1 * sn;
    dst[1] = a0 * sn + a1 * cs;
  } else if (n < 5120) {  // k
    const int nn = n - 4096;
    const int h = nn >> 7;
    const int j = (nn & 127) >> 1;
    const float invf = powf(10000.0f, -(float)j * (1.0f / 64.0f));
    float sn, cs;
    sincosf((float)h * invf, &sn, &cs);
    float* dst = kw + ((size_t)(b * NKV + h) * Tt + t) * HD + (j << 1);
    dst[0] = a0 * cs - a1 * sn;
    dst[1] = a0 * sn + a1 * cs;
  } else {  // v
    const int nn = n - 5120;
    const int h = nn >> 7;
    const int d = nn & 127;
    float* dst = vw + ((size_t)(b * NKV + h) * Tt + t) * HD + d;
    dst[0] = a0;
    dst[1] = a1;
  }
}

// ---------------------------------------------------------------------------
// Flash-decode attention partials. Block = (b, kv-head g, split). 4 waves =
// 4 GQA q-heads. 32-key chunks staged in LDS with register prefetch.
// ---------------------------------------------------------------------------
__global__ __launch_bounds__(256) void attn_partial(
    const float* __restrict__ qw, const float* __restrict__ kw,
    const float* __restrict__ vw, const float* __restrict__ cacheK,
    const float* __restrict__ cacheV, const int* __restrict__ startp,
    float* __restrict__ pO, float* __restrict__ pM, float* __restrict__ pL) {
  const int blk = blockIdx.x;
  const int split = blk & (SSPLIT - 1);
  const int g = (blk / SSPLIT) & (NKV - 1);
  const int b = blk / (SSPLIT * NKV);
  const int start = *startp;
  const int end = start + Tt;
  int cl = ((end + SSPLIT * 32 - 1) / (SSPLIT * 32)) * 32;
  const int s_begin = split * cl;
  int s_end = s_begin + cl;
  if (s_end > end) s_end = end;

  const int tid = threadIdx.x;
  const int lane = tid & 63;
  const int wave = tid >> 6;
  const int l15 = lane & 15;
  const int quad = lane >> 4;
  const int h = g * 4 + wave;

  __shared__ _Float16 Ks[32][136];
  __shared__ _Float16 Vt[128][40];   // transposed V: d x keys
  __shared__ _Float16 Ps[4][32][40];

  // Q fragments (A-operand)
  half8 qf[2][4];
#pragma unroll
  for (int mt = 0; mt < 2; mt++) {
    const int t = mt * 16 + l15;
    const float* qrow = qw + ((size_t)(b * NQ + h) * Tt + t) * HD;
#pragma unroll
    for (int ks = 0; ks < 4; ks++) {
      const int d0 = ks * 32 + quad * 8;
      float4 v0 = *(const float4*)&qrow[d0];
      float4 v1 = *(const float4*)&qrow[d0 + 4];
      half8 hq = {f2h(v0.x), f2h(v0.y), f2h(v0.z), f2h(v0.w),
                  f2h(v1.x), f2h(v1.y), f2h(v1.z), f2h(v1.w)};
      qf[mt][ks] = hq;
    }
  }

  f32x4 Oacc[2][8];
#pragma unroll
  for (int mt = 0; mt < 2; mt++)
#pragma unroll
    for (int dt = 0; dt < 8; dt++) Oacc[mt][dt] = f32x4{0.f, 0.f, 0.f, 0.f};
  float mrow[2][4], lrow[2][4];
#pragma unroll
  for (int mt = 0; mt < 2; mt++)
#pragma unroll
    for (int rr = 0; rr < 4; rr++) { mrow[mt][rr] = -1e30f; lrow[mt][rr] = 0.f; }

  // staging assignment
  const int str = tid >> 3;        // key row 0..31
  const int stc = (tid & 7) * 4;   // col base (floats), +u*32

  float4 pk[4], pv[4];
  auto load_chunk = [&](int s0) {
    const int sg = s0 + str;
    const bool valid = sg < end;
    const float* krow;
    const float* vrow;
    if (sg < start) {
      const size_t off = (((size_t)b * CACHE_S + sg) * NKV + g) * HD;
      krow = cacheK + off;
      vrow = cacheV + off;
    } else {
      int loc = sg - start;
      if (loc > Tt - 1) loc = Tt - 1;
      const size_t off = ((size_t)(b * NKV + g) * Tt + loc) * HD;
      krow = kw + off;
      vrow = vw + off;
    }
#pragma unroll
    for (int u = 0; u < 4; u++) {
      const int cc = stc + u * 32;
      pk[u] = valid ? *(const float4*)&krow[cc] : make_float4(0.f, 0.f, 0.f, 0.f);
      pv[u] = valid ? *(const float4*)&vrow[cc] : make_float4(0.f, 0.f, 0.f, 0.f);
    }
  };

  load_chunk(s_begin);

  for (int s0 = s_begin; s0 < s_end; s0 += 32) {
    __syncthreads();
#pragma unroll
    for (int u = 0; u < 4; u++) {
      const int cc = stc + u * 32;
      half4 hk = {f2h(pk[u].x), f2h(pk[u].y), f2h(pk[u].z), f2h(pk[u].w)};
      *(half4*)&Ks[str][cc] = hk;
      Vt[cc + 0][str] = f2h(pv[u].x);
      Vt[cc + 1][str] = f2h(pv[u].y);
      Vt[cc + 2][str] = f2h(pv[u].z);
      Vt[cc + 3][str] = f2h(pv[u].w);
    }
    __syncthreads();
    if (s0 + 32 < s_end) load_chunk(s0 + 32);  // overlaps with compute below

    // ---- scores ----
    f32x4 st[2][2];
#pragma unroll
    for (int mt = 0; mt < 2; mt++)
#pragma unroll
      for (int nt = 0; nt < 2; nt++) st[mt][nt] = f32x4{0.f, 0.f, 0.f, 0.f};
#pragma unroll
    for (int nt = 0; nt < 2; nt++) {
#pragma unroll
      for (int ks = 0; ks < 4; ks++) {
        half8 kf = *(const half8*)&Ks[nt * 16 + l15][ks * 32 + quad * 8];
        st[0][nt] = __builtin_amdgcn_mfma_f32_16x16x32_f16(qf[0][ks], kf, st[0][nt], 0, 0, 0);
        st[1][nt] = __builtin_amdgcn_mfma_f32_16x16x32_f16(qf[1][ks], kf, st[1][nt], 0, 0, 0);
      }
    }
#pragma unroll
    for (int mt = 0; mt < 2; mt++)
#pragma unroll
      for (int nt = 0; nt < 2; nt++)
#pragma unroll
        for (int rr = 0; rr < 4; rr++) {
          const int t = mt * 16 + quad * 4 + rr;
          const int sg = s0 + nt * 16 + l15;
          const float sv = st[mt][nt][rr] * SCALE_F;
          const bool masked = (sg > start + t) || (sg >= end);
          st[mt][nt][rr] = masked ? -1e30f : sv;
        }
    // ---- online softmax ----
#pragma unroll
    for (int mt = 0; mt < 2; mt++) {
      float rmax[4], rsum[4], al[4];
#pragma unroll
      for (int rr = 0; rr < 4; rr++)
        rmax[rr] = fmaxf(st[mt][0][rr], st[mt][1][rr]);
      for (int mm = 1; mm < 16; mm <<= 1)
#pragma unroll
        for (int rr = 0; rr < 4; rr++)
          rmax[rr] = fmaxf(rmax[rr], __shfl_xor(rmax[rr], mm));
#pragma unroll
      for (int rr = 0; rr < 4; rr++) {
        const float mn = fmaxf(mrow[mt][rr], rmax[rr]);
        al[rr] = __expf(mrow[mt][rr] - mn);
        mrow[mt][rr] = mn;
      }
#pragma unroll
      for (int nt = 0; nt < 2; nt++)
#pragma unroll
        for (int rr = 0; rr < 4; rr++)
          st[mt][nt][rr] = __expf(st[mt][nt][rr] - mrow[mt][rr]);
#pragma unroll
      for (int rr = 0; rr < 4; rr++) rsum[rr] = st[mt][0][rr] + st[mt][1][rr];
      for (int mm = 1; mm < 16; mm <<= 1)
#pragma unroll
        for (int rr = 0; rr < 4; rr++) rsum[rr] += __shfl_xor(rsum[rr], mm);
#pragma unroll
      for (int rr = 0; rr < 4; rr++)
        lrow[mt][rr] = lrow[mt][rr] * al[rr] + rsum[rr];
#pragma unroll
      for (int nt = 0; nt < 2; nt++)
#pragma unroll
        for (int rr = 0; rr < 4; rr++)
          Ps[wave][mt * 16 + quad * 4 + rr][nt * 16 + l15] = f2h(st[mt][nt][rr]);
#pragma unroll
      for (int dt = 0; dt < 8; dt++)
#pragma unroll
        for (int rr = 0; rr < 4; rr++) Oacc[mt][dt][rr] *= al[rr];
    }
    // ---- PV ----
    half8 pf0 = *(const half8*)&Ps[wave][l15][quad * 8];
    half8 pf1 = *(const half8*)&Ps[wave][16 + l15][quad * 8];
#pragma unroll
    for (int dt = 0; dt < 8; dt++) {
      half8 vf = *(const half8*)&Vt[dt * 16 + l15][quad * 8];
      Oacc[0][dt] = __builtin_amdgcn_mfma_f32_16x16x32_f16(pf0, vf, Oacc[0][dt], 0, 0, 0);
      Oacc[1][dt] = __builtin_amdgcn_mfma_f32_16x16x32_f16(pf1, vf, Oacc[1][dt], 0, 0, 0);
    }
  }

  const size_t rowbase = (size_t)(b * NQ + h) * Tt;
#pragma unroll
  for (int mt = 0; mt < 2; mt++)
#pragma unroll
    for (int rr = 0; rr < 4; rr++) {
      const int t = mt * 16 + quad * 4 + rr;
      const size_t pbase = ((rowbase + t) * SSPLIT + split) * (size_t)HD;
#pragma unroll
      for (int dt = 0; dt < 8; dt++)
        pO[pbase + dt * 16 + l15] = Oacc[mt][dt][rr];
      if (l15 == 0) {
        pM[(rowbase + t) * SSPLIT + split] = mrow[mt][rr];
        pL[(rowbase + t) * SSPLIT + split] = lrow[mt][rr];
      }
    }
}

// ---------------------------------------------------------------------------
__global__ __launch_bounds__(128) void attn_combine(
    const float* __restrict__ pO, const float* __restrict__ pM,
    const float* __restrict__ pL, float* __restrict__ att) {
  const int row = blockIdx.x;  // (b*NQ + h)*T + t
  const int d = threadIdx.x;
  float m[SSPLIT], l[SSPLIT];
  float ms = -3.0e30f;
#pragma unroll
  for (int i = 0; i < SSPLIT; i++) {
    m[i] = pM[row * SSPLIT + i];
    l[i] = pL[row * SSPLIT + i];
    ms = fmaxf(ms, m[i]);
  }
  float ls = 0.f, o = 0.f;
#pragma unroll
  for (int i = 0; i < SSPLIT; i++) {
    const float w = __expf(m[i] - ms);
    ls += l[i] * w;
    o += pO[((size_t)row * SSPLIT + i) * HD + d] * w;
  }
  o /= fmaxf(ls, 1e-30f);
  const int b = row / (NQ * Tt);
  const int hh = (row / Tt) % NQ;
  const int t = row % Tt;
  att[((size_t)(b * Tt + t)) * Ee + hh * HD + d] = o;
}

// ---------------------------------------------------------------------------
extern "C" void kernel_launch(void* const* d_in, const int* in_sizes, int n_in,
                              void* d_out, int out_size, void* d_ws,
                              size_t ws_size, hipStream_t stream) {
  const float* x = (const float*)d_in[0];
  const int* startp = (const int*)d_in[1];
  const float* cacheK = (const float*)d_in[2];
  const float* cacheV = (const float*)d_in[3];
  const float* Wq = (const float*)d_in[4];
  const float* Wk = (const float*)d_in[5];
  const float* Wv = (const float*)d_in[6];
  const float* Wo = (const float*)d_in[7];
  float* out = (float*)d_out;
  float* ws = (float*)d_ws;

  // workspace layout (floats); qkv overlays the pO region (dead after rope)
  float* qkv = ws;                      // 256*6144 = 1,572,864
  float* pO = ws;                       // 8192*SSPLIT*128 = 8,388,608
  float* qw = ws + 8388608;             // 1,048,576
  float* kw = qw + 1048576;             // 262,144
  float* vw = kw + 262144;              // 262,144
  float* pM = vw + 262144;              // 65,536
  float* pL = pM + 65536;               // 65,536
  float* att = pL + 65536;              // 1,048,576

  const dim3 blk(256);
  // QKV projections
  gemm_nt<<<dim3(64, 4), blk, 0, stream>>>(x, Wq, Wq, 4096, qkv, 4096, 6144);
  gemm_nt<<<dim3(32, 4), blk, 0, stream>>>(x, Wk, Wv, 1024, qkv + 4096, 4096, 6144);
  // RoPE + scatter
  rope_scatter<<<dim3(3072), blk, 0, stream>>>(qkv, qw, kw, vw);
  // Attention
  attn_partial<<<dim3(Bb * NKV * SSPLIT), blk, 0, stream>>>(
      qw, kw, vw, cacheK, cacheV, startp, pO, pM, pL);
  attn_combine<<<dim3(Bb * NQ * Tt), dim3(128), 0, stream>>>(pO, pM, pL, att);
  // Output projection
  gemm_nt<<<dim3(64, 4), blk, 0, stream>>>(att, Wo, Wo, 4096, out, 4096, 4096);
}

// Round 3
// 652.881 us; speedup vs baseline: 1.7892x; 1.1557x over previous
//
#include <hip/hip_runtime.h>
#include <stdint.h>

#define Bb 8
#define Tt 32
#define Ee 4096
#define NQ 32
#define NKV 8
#define HD 128
#define CACHE_S 8192
#define SSPLIT 8
#define SCALE_F 0.08838834764831845f  // 1/sqrt(128)

typedef _Float16 half8 __attribute__((ext_vector_type(8)));
typedef _Float16 half4 __attribute__((ext_vector_type(4)));
typedef float f32x4 __attribute__((ext_vector_type(4)));

static __device__ __forceinline__ _Float16 f2h(float f) { return (_Float16)f; }

// ---------------------------------------------------------------------------
// Split-K GEMM: Cpart[z] = A[Mx Kc] * W[N x Kc]^T for K-chunk z. fp32 in/out,
// f16 MFMA. 64x64 tiles. Weight selected among {W0,W1,W2} by n0 (fused QKV).
// ---------------------------------------------------------------------------
__global__ __launch_bounds__(256) void gemm_nt_sk(
    const float* __restrict__ A, const float* __restrict__ W0,
    const float* __restrict__ W1, const float* __restrict__ W2,
    int nsplit1, int nsplit2, float* __restrict__ Cpart, size_t part_stride,
    int K, int Kc, int ldc) {
  __shared__ _Float16 As[64][72];
  __shared__ _Float16 Ws[64][72];
  const int n0 = blockIdx.x * 64;
  const int m0 = blockIdx.y * 64;
  const int kp = blockIdx.z;
  const int kbase = kp * Kc;
  const float* Wp;
  int nr0;
  if (n0 < nsplit1) { Wp = W0; nr0 = n0; }
  else if (n0 < nsplit2) { Wp = W1; nr0 = n0 - nsplit1; }
  else { Wp = W2; nr0 = n0 - nsplit2; }
  const int tid = threadIdx.x;
  const int lane = tid & 63;
  const int wave = tid >> 6;
  const int wm = (wave >> 1) * 32;
  const int wn = (wave & 1) * 32;
  const int l15 = lane & 15;
  const int quad = lane >> 4;
  const int sr = tid >> 4;        // staging row 0..15 (+p*16)
  const int sc = (tid & 15) * 4;  // staging col (floats)

  f32x4 acc[2][2];
#pragma unroll
  for (int i = 0; i < 2; i++)
#pragma unroll
    for (int j = 0; j < 2; j++) acc[i][j] = f32x4{0.f, 0.f, 0.f, 0.f};

  float4 pa[4], pw[4];
#pragma unroll
  for (int p = 0; p < 4; p++) {
    const int r = sr + p * 16;
    pa[p] = *(const float4*)&A[(size_t)(m0 + r) * K + kbase + sc];
    pw[p] = *(const float4*)&Wp[(size_t)(nr0 + r) * K + kbase + sc];
  }

  for (int k0 = 0; k0 < Kc; k0 += 64) {
    __syncthreads();
#pragma unroll
    for (int p = 0; p < 4; p++) {
      const int r = sr + p * 16;
      half4 ha = {f2h(pa[p].x), f2h(pa[p].y), f2h(pa[p].z), f2h(pa[p].w)};
      *(half4*)&As[r][sc] = ha;
      half4 hw = {f2h(pw[p].x), f2h(pw[p].y), f2h(pw[p].z), f2h(pw[p].w)};
      *(half4*)&Ws[r][sc] = hw;
    }
    __syncthreads();
    if (k0 + 64 < Kc) {  // prefetch next K-tile (overlaps MFMA below)
#pragma unroll
      for (int p = 0; p < 4; p++) {
        const int r = sr + p * 16;
        pa[p] = *(const float4*)&A[(size_t)(m0 + r) * K + kbase + k0 + 64 + sc];
        pw[p] = *(const float4*)&Wp[(size_t)(nr0 + r) * K + kbase + k0 + 64 + sc];
      }
    }
#pragma unroll
    for (int ks = 0; ks < 2; ks++) {
      const int kc = ks * 32 + quad * 8;
      half8 af[2], wf[2];
#pragma unroll
      for (int i = 0; i < 2; i++) {
        af[i] = *(const half8*)&As[wm + i * 16 + l15][kc];
        wf[i] = *(const half8*)&Ws[wn + i * 16 + l15][kc];
      }
#pragma unroll
      for (int i = 0; i < 2; i++)
#pragma unroll
        for (int j = 0; j < 2; j++)
          acc[i][j] = __builtin_amdgcn_mfma_f32_16x16x32_f16(af[i], wf[j],
                                                             acc[i][j], 0, 0, 0);
    }
  }
  float* Cp = Cpart + (size_t)kp * part_stride;
#pragma unroll
  for (int i = 0; i < 2; i++) {
    const int mr = m0 + wm + i * 16 + quad * 4;
#pragma unroll
    for (int j = 0; j < 2; j++) {
      const int nc = n0 + wn + j * 16 + l15;
#pragma unroll
      for (int r = 0; r < 4; r++)
        Cp[(size_t)(mr + r) * ldc + nc] = acc[i][j][r];
    }
  }
}

// ---------------------------------------------------------------------------
// Sum 4 split-K partials of qkv + RoPE (bugged: angle from HEAD index) +
// scatter to qw (B,NQ,T,HD), kw/vw (B,NKV,T,HD).
// ---------------------------------------------------------------------------
__global__ __launch_bounds__(256) void rope_scatter(
    const float* __restrict__ qkvp, float* __restrict__ qw,
    float* __restrict__ kw, float* __restrict__ vw) {
  const int pid = blockIdx.x * 256 + threadIdx.x;
  const int m = pid / 3072;
  const int c = pid - m * 3072;
  const int n = c * 2;
  const int b = m >> 5;
  const int t = m & 31;
  const size_t base = (size_t)m * 6144 + n;
  float a0 = 0.f, a1 = 0.f;
#pragma unroll
  for (int p = 0; p < 4; p++) {
    const float2 v = *(const float2*)&qkvp[p * 1572864 + base];
    a0 += v.x;
    a1 += v.y;
  }
  if (n < 4096) {  // q
    const int h = n >> 7;
    const int j = (n & 127) >> 1;
    const float invf = powf(10000.0f, -(float)j * (1.0f / 64.0f));
    float sn, cs;
    sincosf((float)h * invf, &sn, &cs);
    float* dst = qw + ((size_t)(b * NQ + h) * Tt + t) * HD + (j << 1);
    dst[0] = a0 * cs - a1 * sn;
    dst[1] = a0 * sn + a1 * cs;
  } else if (n < 5120) {  // k
    const int nn = n - 4096;
    const int h = nn >> 7;
    const int j = (nn & 127) >> 1;
    const float invf = powf(10000.0f, -(float)j * (1.0f / 64.0f));
    float sn, cs;
    sincosf((float)h * invf, &sn, &cs);
    float* dst = kw + ((size_t)(b * NKV + h) * Tt + t) * HD + (j << 1);
    dst[0] = a0 * cs - a1 * sn;
    dst[1] = a0 * sn + a1 * cs;
  } else {  // v
    const int nn = n - 5120;
    const int h = nn >> 7;
    const int d = nn & 127;
    float* dst = vw + ((size_t)(b * NKV + h) * Tt + t) * HD + d;
    dst[0] = a0;
    dst[1] = a1;
  }
}

// ---------------------------------------------------------------------------
// Flash-decode attention partials. Block = (b, kv-head g, split). 4 waves =
// 4 GQA q-heads. 32-key chunks staged in LDS with register prefetch.
// ---------------------------------------------------------------------------
__global__ __launch_bounds__(256) void attn_partial(
    const float* __restrict__ qw, const float* __restrict__ kw,
    const float* __restrict__ vw, const float* __restrict__ cacheK,
    const float* __restrict__ cacheV, const int* __restrict__ startp,
    float* __restrict__ pO, float* __restrict__ pM, float* __restrict__ pL) {
  const int blk = blockIdx.x;
  const int split = blk & (SSPLIT - 1);
  const int g = (blk / SSPLIT) & (NKV - 1);
  const int b = blk / (SSPLIT * NKV);
  const int start = *startp;
  const int end = start + Tt;
  int cl = ((end + SSPLIT * 32 - 1) / (SSPLIT * 32)) * 32;
  const int s_begin = split * cl;
  int s_end = s_begin + cl;
  if (s_end > end) s_end = end;

  const int tid = threadIdx.x;
  const int lane = tid & 63;
  const int wave = tid >> 6;
  const int l15 = lane & 15;
  const int quad = lane >> 4;
  const int h = g * 4 + wave;

  __shared__ _Float16 Ks[32][136];
  __shared__ _Float16 Vt[128][40];   // transposed V: d x keys
  __shared__ _Float16 Ps[4][32][40];

  // Q fragments (A-operand)
  half8 qf[2][4];
#pragma unroll
  for (int mt = 0; mt < 2; mt++) {
    const int t = mt * 16 + l15;
    const float* qrow = qw + ((size_t)(b * NQ + h) * Tt + t) * HD;
#pragma unroll
    for (int ks = 0; ks < 4; ks++) {
      const int d0 = ks * 32 + quad * 8;
      float4 v0 = *(const float4*)&qrow[d0];
      float4 v1 = *(const float4*)&qrow[d0 + 4];
      half8 hq = {f2h(v0.x), f2h(v0.y), f2h(v0.z), f2h(v0.w),
                  f2h(v1.x), f2h(v1.y), f2h(v1.z), f2h(v1.w)};
      qf[mt][ks] = hq;
    }
  }

  f32x4 Oacc[2][8];
#pragma unroll
  for (int mt = 0; mt < 2; mt++)
#pragma unroll
    for (int dt = 0; dt < 8; dt++) Oacc[mt][dt] = f32x4{0.f, 0.f, 0.f, 0.f};
  float mrow[2][4], lrow[2][4];
#pragma unroll
  for (int mt = 0; mt < 2; mt++)
#pragma unroll
    for (int rr = 0; rr < 4; rr++) { mrow[mt][rr] = -1e30f; lrow[mt][rr] = 0.f; }

  const int str = tid >> 3;        // key row 0..31
  const int stc = (tid & 7) * 4;   // col base (floats), +u*32

  float4 pk[4], pv[4];
  auto load_chunk = [&](int s0) {
    const int sg = s0 + str;
    const bool valid = sg < end;
    const float* krow;
    const float* vrow;
    if (sg < start) {
      const size_t off = (((size_t)b * CACHE_S + sg) * NKV + g) * HD;
      krow = cacheK + off;
      vrow = cacheV + off;
    } else {
      int loc = sg - start;
      if (loc > Tt - 1) loc = Tt - 1;
      const size_t off = ((size_t)(b * NKV + g) * Tt + loc) * HD;
      krow = kw + off;
      vrow = vw + off;
    }
#pragma unroll
    for (int u = 0; u < 4; u++) {
      const int cc = stc + u * 32;
      pk[u] = valid ? *(const float4*)&krow[cc] : make_float4(0.f, 0.f, 0.f, 0.f);
      pv[u] = valid ? *(const float4*)&vrow[cc] : make_float4(0.f, 0.f, 0.f, 0.f);
    }
  };

  load_chunk(s_begin);

  for (int s0 = s_begin; s0 < s_end; s0 += 32) {
    __syncthreads();
#pragma unroll
    for (int u = 0; u < 4; u++) {
      const int cc = stc + u * 32;
      half4 hk = {f2h(pk[u].x), f2h(pk[u].y), f2h(pk[u].z), f2h(pk[u].w)};
      *(half4*)&Ks[str][cc] = hk;
      Vt[cc + 0][str] = f2h(pv[u].x);
      Vt[cc + 1][str] = f2h(pv[u].y);
      Vt[cc + 2][str] = f2h(pv[u].z);
      Vt[cc + 3][str] = f2h(pv[u].w);
    }
    __syncthreads();
    if (s0 + 32 < s_end) load_chunk(s0 + 32);  // overlaps compute below

    // ---- scores ----
    f32x4 st[2][2];
#pragma unroll
    for (int mt = 0; mt < 2; mt++)
#pragma unroll
      for (int nt = 0; nt < 2; nt++) st[mt][nt] = f32x4{0.f, 0.f, 0.f, 0.f};
#pragma unroll
    for (int nt = 0; nt < 2; nt++) {
#pragma unroll
      for (int ks = 0; ks < 4; ks++) {
        half8 kf = *(const half8*)&Ks[nt * 16 + l15][ks * 32 + quad * 8];
        st[0][nt] = __builtin_amdgcn_mfma_f32_16x16x32_f16(qf[0][ks], kf, st[0][nt], 0, 0, 0);
        st[1][nt] = __builtin_amdgcn_mfma_f32_16x16x32_f16(qf[1][ks], kf, st[1][nt], 0, 0, 0);
      }
    }
#pragma unroll
    for (int mt = 0; mt < 2; mt++)
#pragma unroll
      for (int nt = 0; nt < 2; nt++)
#pragma unroll
        for (int rr = 0; rr < 4; rr++) {
          const int t = mt * 16 + quad * 4 + rr;
          const int sg = s0 + nt * 16 + l15;
          const float sv = st[mt][nt][rr] * SCALE_F;
          const bool masked = (sg > start + t) || (sg >= end);
          st[mt][nt][rr] = masked ? -1e30f : sv;
        }
    // ---- online softmax ----
#pragma unroll
    for (int mt = 0; mt < 2; mt++) {
      float rmax[4], rsum[4], al[4];
#pragma unroll
      for (int rr = 0; rr < 4; rr++)
        rmax[rr] = fmaxf(st[mt][0][rr], st[mt][1][rr]);
      for (int mm = 1; mm < 16; mm <<= 1)
#pragma unroll
        for (int rr = 0; rr < 4; rr++)
          rmax[rr] = fmaxf(rmax[rr], __shfl_xor(rmax[rr], mm));
#pragma unroll
      for (int rr = 0; rr < 4; rr++) {
        const float mn = fmaxf(mrow[mt][rr], rmax[rr]);
        al[rr] = __expf(mrow[mt][rr] - mn);
        mrow[mt][rr] = mn;
      }
#pragma unroll
      for (int nt = 0; nt < 2; nt++)
#pragma unroll
        for (int rr = 0; rr < 4; rr++)
          st[mt][nt][rr] = __expf(st[mt][nt][rr] - mrow[mt][rr]);
#pragma unroll
      for (int rr = 0; rr < 4; rr++) rsum[rr] = st[mt][0][rr] + st[mt][1][rr];
      for (int mm = 1; mm < 16; mm <<= 1)
#pragma unroll
        for (int rr = 0; rr < 4; rr++) rsum[rr] += __shfl_xor(rsum[rr], mm);
#pragma unroll
      for (int rr = 0; rr < 4; rr++)
        lrow[mt][rr] = lrow[mt][rr] * al[rr] + rsum[rr];
#pragma unroll
      for (int nt = 0; nt < 2; nt++)
#pragma unroll
        for (int rr = 0; rr < 4; rr++)
          Ps[wave][mt * 16 + quad * 4 + rr][nt * 16 + l15] = f2h(st[mt][nt][rr]);
#pragma unroll
      for (int dt = 0; dt < 8; dt++)
#pragma unroll
        for (int rr = 0; rr < 4; rr++) Oacc[mt][dt][rr] *= al[rr];
    }
    // ---- PV ----
    half8 pf0 = *(const half8*)&Ps[wave][l15][quad * 8];
    half8 pf1 = *(const half8*)&Ps[wave][16 + l15][quad * 8];
#pragma unroll
    for (int dt = 0; dt < 8; dt++) {
      half8 vf = *(const half8*)&Vt[dt * 16 + l15][quad * 8];
      Oacc[0][dt] = __builtin_amdgcn_mfma_f32_16x16x32_f16(pf0, vf, Oacc[0][dt], 0, 0, 0);
      Oacc[1][dt] = __builtin_amdgcn_mfma_f32_16x16x32_f16(pf1, vf, Oacc[1][dt], 0, 0, 0);
    }
  }

  const size_t rowbase = (size_t)(b * NQ + h) * Tt;
#pragma unroll
  for (int mt = 0; mt < 2; mt++)
#pragma unroll
    for (int rr = 0; rr < 4; rr++) {
      const int t = mt * 16 + quad * 4 + rr;
      const size_t pbase = ((rowbase + t) * SSPLIT + split) * (size_t)HD;
#pragma unroll
      for (int dt = 0; dt < 8; dt++)
        pO[pbase + dt * 16 + l15] = Oacc[mt][dt][rr];
      if (l15 == 0) {
        pM[(rowbase + t) * SSPLIT + split] = mrow[mt][rr];
        pL[(rowbase + t) * SSPLIT + split] = lrow[mt][rr];
      }
    }
}

// ---------------------------------------------------------------------------
__global__ __launch_bounds__(128) void attn_combine(
    const float* __restrict__ pO, const float* __restrict__ pM,
    const float* __restrict__ pL, float* __restrict__ att) {
  const int row = blockIdx.x;  // (b*NQ + h)*T + t
  const int d = threadIdx.x;
  float m[SSPLIT], l[SSPLIT];
  float ms = -3.0e30f;
#pragma unroll
  for (int i = 0; i < SSPLIT; i++) {
    m[i] = pM[row * SSPLIT + i];
    l[i] = pL[row * SSPLIT + i];
    ms = fmaxf(ms, m[i]);
  }
  float ls = 0.f, o = 0.f;
#pragma unroll
  for (int i = 0; i < SSPLIT; i++) {
    const float w = __expf(m[i] - ms);
    ls += l[i] * w;
    o += pO[((size_t)row * SSPLIT + i) * HD + d] * w;
  }
  o /= fmaxf(ls, 1e-30f);
  const int b = row / (NQ * Tt);
  const int hh = (row / Tt) % NQ;
  const int t = row % Tt;
  att[((size_t)(b * Tt + t)) * Ee + hh * HD + d] = o;
}

// ---------------------------------------------------------------------------
// out = p0 + p1 (Wo split-K reduce), float4-vectorized.
// ---------------------------------------------------------------------------
__global__ __launch_bounds__(256) void reduce2(const float* __restrict__ p0,
                                               const float* __restrict__ p1,
                                               float* __restrict__ out) {
  const int i = (blockIdx.x * 256 + threadIdx.x) * 4;
  float4 a = *(const float4*)&p0[i];
  float4 b = *(const float4*)&p1[i];
  float4 r = make_float4(a.x + b.x, a.y + b.y, a.z + b.z, a.w + b.w);
  *(float4*)&out[i] = r;
}

// ---------------------------------------------------------------------------
extern "C" void kernel_launch(void* const* d_in, const int* in_sizes, int n_in,
                              void* d_out, int out_size, void* d_ws,
                              size_t ws_size, hipStream_t stream) {
  const float* x = (const float*)d_in[0];
  const int* startp = (const int*)d_in[1];
  const float* cacheK = (const float*)d_in[2];
  const float* cacheV = (const float*)d_in[3];
  const float* Wq = (const float*)d_in[4];
  const float* Wk = (const float*)d_in[5];
  const float* Wv = (const float*)d_in[6];
  const float* Wo = (const float*)d_in[7];
  float* out = (float*)d_out;
  float* ws = (float*)d_ws;

  // workspace layout (floats)
  float* qkvp = ws;                     // 4 x 1,572,864 = 6,291,456
  float* pO = qkvp + 6291456;           // 8192*SSPLIT*128 = 8,388,608
  float* qw = pO + 8388608;             // 1,048,576
  float* kw = qw + 1048576;             // 262,144
  float* vw = kw + 262144;              // 262,144
  float* pM = vw + 262144;              // 65,536
  float* pL = pM + 65536;               // 65,536
  float* att = pL + 65536;              // 1,048,576
  float* woP = att + 1048576;           // 2 x 1,048,576

  const dim3 blk(256);
  // Fused QKV projection, split-K=4: grid 96x4x4 = 1536 blocks
  gemm_nt_sk<<<dim3(96, 4, 4), blk, 0, stream>>>(
      x, Wq, Wk, Wv, 4096, 5120, qkvp, (size_t)256 * 6144, 4096, 1024, 6144);
  // RoPE + split-K reduce + scatter
  rope_scatter<<<dim3(3072), blk, 0, stream>>>(qkvp, qw, kw, vw);
  // Attention
  attn_partial<<<dim3(Bb * NKV * SSPLIT), blk, 0, stream>>>(
      qw, kw, vw, cacheK, cacheV, startp, pO, pM, pL);
  attn_combine<<<dim3(Bb * NQ * Tt), dim3(128), 0, stream>>>(pO, pM, pL, att);
  // Output projection, split-K=2: grid 64x4x2 = 512 blocks
  gemm_nt_sk<<<dim3(64, 4, 2), blk, 0, stream>>>(
      att, Wo, Wo, Wo, 4096, 4096, woP, (size_t)256 * 4096, 4096, 2048, 4096);
  reduce2<<<dim3(1024), blk, 0, stream>>>(woP, woP + 1048576, out);
}